// Round 17
// baseline (533.576 us; speedup 1.0000x reference)
//
#include <hip/hip_runtime.h>
#include <hip/hip_bf16.h>

#define SEQ      1024
#define BATCH    4
#define NHEADS   16
#define HDIM     64
#define DMODEL   1024
#define DGRAPH   8
#define QK_SCALE 0.125f
#define PCONST   0.0009765625f   /* 1/1024 exact */

typedef __attribute__((ext_vector_type(8))) short bf16x8;
typedef __attribute__((ext_vector_type(4))) short bf16x4;
typedef __attribute__((ext_vector_type(4))) float f32x4;

__device__ __forceinline__ void split_bf16(float x, short& hi, short& lo) {
    unsigned u = __float_as_uint(x);
    hi = (short)(u >> 16);                         // truncated high part
    float hf = __uint_as_float(u & 0xffff0000u);
    lo = (short)(__float_as_uint(x - hf) >> 16);   // residual, truncated
}

__device__ __forceinline__ short f2bf_rne(float x) {   // RNE bf16
    unsigned u = __float_as_uint(x);
    u += 0x7fffu + ((u >> 16) & 1u);
    return (short)(u >> 16);
}

__global__ void zero_f32(float* p, int n) {
    int i = blockIdx.x * 256 + threadIdx.x;
    if (i < n) p[i] = 0.f;
}

// ---------------------------------------------------------------------------
// One-time hi/lo split of the fused weight matrix (4M floats).
// ---------------------------------------------------------------------------
__global__ __launch_bounds__(256) void prep_split(
    const float* __restrict__ X, short* __restrict__ Hi, short* __restrict__ Lo)
{
    const int idx = blockIdx.x * 256 + threadIdx.x;
    const float* p = X + (size_t)idx * 8;
    float4 u0 = *(const float4*)p;
    float4 u1 = *(const float4*)(p + 4);
    float v[8] = {u0.x, u0.y, u0.z, u0.w, u1.x, u1.y, u1.z, u1.w};
    bf16x8 hv, lv;
#pragma unroll
    for (int j = 0; j < 8; ++j) {
        short h, s; split_bf16(v[j], h, s);
        hv[j] = h; lv[j] = s;
    }
    *(bf16x8*)(Hi + (size_t)idx * 8) = hv;
    *(bf16x8*)(Lo + (size_t)idx * 8) = lv;
}

// ---------------------------------------------------------------------------
// Split-bf16 MFMA projection (structure proven r5-r12, unchanged).
// INMODE 0: X fp32 (split in staging)    INMODE 1: X pre-split (Xhi/Xlo)
// OUTMODE 0: fp32 flat [m][DMODEL]
// OUTMODE 2: bf16 hi/lo headsplit [b][h][n][d]
// OUTMODE 3: bf16 hi/lo head-transposed [b][h][d][n]
// ---------------------------------------------------------------------------
template<int INMODE, int OUTMODE>
__global__ __launch_bounds__(256) void proj_mfma(
    const float* __restrict__ X,
    const short* __restrict__ Xhi, const short* __restrict__ Xlo,
    const short* __restrict__ Whi, const short* __restrict__ Wlo,
    const float* __restrict__ bias,
    float* __restrict__ Yf,
    short* __restrict__ Yhi,
    short* __restrict__ Ylo,
    float scale)
{
    constexpr int LDK = 40;
    __shared__ short Ah[128 * LDK];
    __shared__ short Al[128 * LDK];
    __shared__ short Bh[64 * LDK];
    __shared__ short Bl[64 * LDK];

    const int t   = threadIdx.x;
    const int w   = t >> 6;
    const int l   = t & 63;
    const int l15 = l & 15;
    const int lk  = (l >> 4) * 8;
    const int m0  = blockIdx.y * 128;
    const int c0  = blockIdx.x * 64;
    const int wr  = (w >> 1) * 64;
    const int wc  = (w & 1) * 32;

    const int srow = t >> 2;
    const int skg  = t & 3;

    f32x4 acc[4][2];
#pragma unroll
    for (int i = 0; i < 4; ++i)
#pragma unroll
        for (int j = 0; j < 2; ++j) acc[i][j] = f32x4{0.f, 0.f, 0.f, 0.f};

    float  xa[2][8];
    bf16x8 xh[2], xl[2];
    bf16x8 wh, wl;

    if constexpr (INMODE == 0) {
#pragma unroll
        for (int i = 0; i < 2; ++i) {
            const float* p = X + (size_t)(m0 + srow + i * 64) * DMODEL + skg * 8;
            float4 u0 = *(const float4*)p;
            float4 u1 = *(const float4*)(p + 4);
            xa[i][0] = u0.x; xa[i][1] = u0.y; xa[i][2] = u0.z; xa[i][3] = u0.w;
            xa[i][4] = u1.x; xa[i][5] = u1.y; xa[i][6] = u1.z; xa[i][7] = u1.w;
        }
    } else {
#pragma unroll
        for (int i = 0; i < 2; ++i) {
            const size_t off = (size_t)(m0 + srow + i * 64) * DMODEL + skg * 8;
            xh[i] = *(const bf16x8*)(Xhi + off);
            xl[i] = *(const bf16x8*)(Xlo + off);
        }
    }
    {
        const size_t off = (size_t)(c0 + srow) * DMODEL + skg * 8;
        wh = *(const bf16x8*)(Whi + off);
        wl = *(const bf16x8*)(Wlo + off);
    }

    for (int kt = 0; kt < 32; ++kt) {
        if constexpr (INMODE == 0) {
#pragma unroll
            for (int i = 0; i < 2; ++i) {
                bf16x8 hv, lv;
#pragma unroll
                for (int j = 0; j < 8; ++j) {
                    short h, s; split_bf16(xa[i][j], h, s);
                    hv[j] = h; lv[j] = s;
                }
                *(bf16x8*)(Ah + (srow + i * 64) * LDK + skg * 8) = hv;
                *(bf16x8*)(Al + (srow + i * 64) * LDK + skg * 8) = lv;
            }
        } else {
#pragma unroll
            for (int i = 0; i < 2; ++i) {
                *(bf16x8*)(Ah + (srow + i * 64) * LDK + skg * 8) = xh[i];
                *(bf16x8*)(Al + (srow + i * 64) * LDK + skg * 8) = xl[i];
            }
        }
        *(bf16x8*)(Bh + srow * LDK + skg * 8) = wh;
        *(bf16x8*)(Bl + srow * LDK + skg * 8) = wl;
        __syncthreads();

        if (kt + 1 < 32) {
            const int k0 = (kt + 1) * 32;
            if constexpr (INMODE == 0) {
#pragma unroll
                for (int i = 0; i < 2; ++i) {
                    const float* p = X + (size_t)(m0 + srow + i * 64) * DMODEL + k0 + skg * 8;
                    float4 u0 = *(const float4*)p;
                    float4 u1 = *(const float4*)(p + 4);
                    xa[i][0] = u0.x; xa[i][1] = u0.y; xa[i][2] = u0.z; xa[i][3] = u0.w;
                    xa[i][4] = u1.x; xa[i][5] = u1.y; xa[i][6] = u1.z; xa[i][7] = u1.w;
                }
            } else {
#pragma unroll
                for (int i = 0; i < 2; ++i) {
                    const size_t off = (size_t)(m0 + srow + i * 64) * DMODEL + k0 + skg * 8;
                    xh[i] = *(const bf16x8*)(Xhi + off);
                    xl[i] = *(const bf16x8*)(Xlo + off);
                }
            }
            const size_t off = (size_t)(c0 + srow) * DMODEL + k0 + skg * 8;
            wh = *(const bf16x8*)(Whi + off);
            wl = *(const bf16x8*)(Wlo + off);
        }

        bf16x8 ah[4], alo[4], bh[2], blo[2];
#pragma unroll
        for (int fm = 0; fm < 4; ++fm) {
            const int off = (wr + fm * 16 + l15) * LDK + lk;
            ah[fm]  = *(const bf16x8*)(Ah + off);
            alo[fm] = *(const bf16x8*)(Al + off);
        }
#pragma unroll
        for (int fn = 0; fn < 2; ++fn) {
            const int off = (wc + fn * 16 + l15) * LDK + lk;
            bh[fn]  = *(const bf16x8*)(Bh + off);
            blo[fn] = *(const bf16x8*)(Bl + off);
        }
#pragma unroll
        for (int fm = 0; fm < 4; ++fm)
#pragma unroll
            for (int fn = 0; fn < 2; ++fn) {
                acc[fm][fn] = __builtin_amdgcn_mfma_f32_16x16x32_bf16(
                    ah[fm], bh[fn], acc[fm][fn], 0, 0, 0);
                acc[fm][fn] = __builtin_amdgcn_mfma_f32_16x16x32_bf16(
                    ah[fm], blo[fn], acc[fm][fn], 0, 0, 0);
                acc[fm][fn] = __builtin_amdgcn_mfma_f32_16x16x32_bf16(
                    alo[fm], bh[fn], acc[fm][fn], 0, 0, 0);
            }
        __syncthreads();
    }

    // epilogue: C/D layout col = l&15, row = (l>>4)*4 + r
#pragma unroll
    for (int fm = 0; fm < 4; ++fm)
#pragma unroll
        for (int fn = 0; fn < 2; ++fn) {
            const int c = c0 + wc + fn * 16 + l15;
            const float bb = bias[c];
#pragma unroll
            for (int r = 0; r < 4; ++r) {
                const int m = m0 + wr + fm * 16 + (l >> 4) * 4 + r;
                const float v = (acc[fm][fn][r] + bb) * scale;
                if constexpr (OUTMODE == 0) {
                    Yf[(size_t)m * DMODEL + c] = v;
                } else {
                    const int b_ = m >> 10, n = m & 1023;
                    const int h = c >> 6, d = c & 63;
                    short hi, lo; split_bf16(v, hi, lo);
                    if constexpr (OUTMODE == 2) {
                        const size_t idx =
                            ((size_t)((b_ * NHEADS + h) * SEQ + n)) * HDIM + d;
                        Yhi[idx] = hi; Ylo[idx] = lo;
                    } else {  // OUTMODE 3: transposed [b][h][d][n]
                        const size_t idx =
                            ((size_t)((b_ * NHEADS + h) * HDIM + d)) * SEQ + n;
                        Yhi[idx] = hi; Ylo[idx] = lo;
                    }
                }
            }
        }
}

// ---------------------------------------------------------------------------
// MFMA QK^T + FUSED graph bias + exp + row-sum. Bias computed on the fly
// from dists (same fmaf order as the old graph_bias kernel -> bit-identical).
// 1D grid, XCD swizzle groups the 16 HEADS of one (b, m0, n0) consecutively
// on one XCD -> the shared 512 KB dists tile is HBM-fetched once, 15x L2-hit.
// Masked rows: no dists read, no E store, no atomic.
// ---------------------------------------------------------------------------
__global__ __launch_bounds__(256) void qk_mfma(
    const short* __restrict__ Qhi, const short* __restrict__ Qlo,
    const short* __restrict__ Khi, const short* __restrict__ Klo,
    const float* __restrict__ dists,
    const float* __restrict__ wg,
    const int* __restrict__ mask,
    float* __restrict__ attL,
    float* __restrict__ rowSum)
{
    constexpr int LDK = 72;
    __shared__ short sQh[128 * LDK];
    __shared__ short sQl[128 * LDK];
    __shared__ short sKh[128 * LDK];
    __shared__ short sKl[128 * LDK];
    __shared__ int maskS[128];

    // swizzle: flat = (bid%512)*8 + bid/512  (bijective, 4096 = 512*8)
    // flat = ((b*64 + j)*16 + h): 16 heads of one (b,j) are consecutive in
    // flat -> same XCD (bid ≡ const mod 8 within the group of 16).
    const int bid  = blockIdx.x;
    const int flat = (bid & 511) * 8 + (bid >> 9);
    const int h    = flat & 15;
    const int j    = (flat >> 4) & 63;
    const int b    = flat >> 10;
    const int m0   = (j & 7) * 128;
    const int n0   = (j >> 3) * 128;
    const int bh   = b * NHEADS + h;

    const int t   = threadIdx.x;
    const int w   = t >> 6;
    const int l   = t & 63;
    const int l15 = l & 15;
    const int lk  = (l >> 4) * 8;

    if (t < 128) maskS[t] = mask[b * SEQ + n0 + t];

    // stage Q/K hi+lo tiles [128][64] bf16 -> padded LDS rows (LDK=72)
#pragma unroll
    for (int it = 0; it < 4; ++it) {
        const int f   = t + it * 256;
        const int row = f >> 3;
        const int c8  = f & 7;
        const size_t gq = ((size_t)bh * SEQ + n0 + row) * HDIM + c8 * 8;
        const size_t gk = ((size_t)bh * SEQ + m0 + row) * HDIM + c8 * 8;
        const int lo = row * LDK + c8 * 8;
        *(bf16x8*)(sQh + lo) = *(const bf16x8*)(Qhi + gq);
        *(bf16x8*)(sQl + lo) = *(const bf16x8*)(Qlo + gq);
        *(bf16x8*)(sKh + lo) = *(const bf16x8*)(Khi + gk);
        *(bf16x8*)(sKl + lo) = *(const bf16x8*)(Klo + gk);
    }
    __syncthreads();   // maskS + LDS tiles ready

    const int nr  = (w >> 1) * 64;   // wave n base
    const int mcw = (w & 1) * 64;    // wave m base

    // wg row for this head (block-uniform)
    float wgv[8];
    {
        float4 w0 = *(const float4*)(wg + h * DGRAPH);
        float4 w1 = *(const float4*)(wg + h * DGRAPH + 4);
        wgv[0] = w0.x; wgv[1] = w0.y; wgv[2] = w0.z; wgv[3] = w0.w;
        wgv[4] = w1.x; wgv[5] = w1.y; wgv[6] = w1.z; wgv[7] = w1.w;
    }

    // acc init = graph bias computed on the fly (masked rows -> 0, no load)
    f32x4 acc[4][4];
#pragma unroll
    for (int fm = 0; fm < 4; ++fm)
#pragma unroll
        for (int r = 0; r < 4; ++r) {
            const int nloc = nr + fm * 16 + (l >> 4) * 4 + r;
            if (maskS[nloc]) {
#pragma unroll
                for (int fn = 0; fn < 4; ++fn) acc[fm][fn][r] = 0.f;
                continue;
            }
            const float* dp = dists +
                (((size_t)(b * SEQ + n0 + nloc)) * SEQ + m0 + mcw + l15) * DGRAPH;
#pragma unroll
            for (int fn = 0; fn < 4; ++fn) {
                float4 d0 = *(const float4*)(dp + fn * 16 * DGRAPH);
                float4 d1 = *(const float4*)(dp + fn * 16 * DGRAPH + 4);
                float s = 0.f;
                s = fmaf(d0.x, wgv[0], s); s = fmaf(d0.y, wgv[1], s);
                s = fmaf(d0.z, wgv[2], s); s = fmaf(d0.w, wgv[3], s);
                s = fmaf(d1.x, wgv[4], s); s = fmaf(d1.y, wgv[5], s);
                s = fmaf(d1.z, wgv[6], s); s = fmaf(d1.w, wgv[7], s);
                acc[fm][fn][r] = s;
            }
        }

#pragma unroll
    for (int ks = 0; ks < 2; ++ks) {
        bf16x8 ah[4], alo[4], bhv[4], blo[4];
#pragma unroll
        for (int fm = 0; fm < 4; ++fm) {
            const int off = (nr + fm * 16 + l15) * LDK + ks * 32 + lk;
            ah[fm]  = *(const bf16x8*)(sQh + off);
            alo[fm] = *(const bf16x8*)(sQl + off);
        }
#pragma unroll
        for (int fn = 0; fn < 4; ++fn) {
            const int off = (mcw + fn * 16 + l15) * LDK + ks * 32 + lk;
            bhv[fn] = *(const bf16x8*)(sKh + off);
            blo[fn] = *(const bf16x8*)(sKl + off);
        }
#pragma unroll
        for (int fm = 0; fm < 4; ++fm)
#pragma unroll
            for (int fn = 0; fn < 4; ++fn) {
                acc[fm][fn] = __builtin_amdgcn_mfma_f32_16x16x32_bf16(
                    ah[fm], bhv[fn], acc[fm][fn], 0, 0, 0);
                acc[fm][fn] = __builtin_amdgcn_mfma_f32_16x16x32_bf16(
                    ah[fm], blo[fn], acc[fm][fn], 0, 0, 0);
                acc[fm][fn] = __builtin_amdgcn_mfma_f32_16x16x32_bf16(
                    alo[fm], bhv[fn], acc[fm][fn], 0, 0, 0);
            }
    }

    // E = exp(S) fp32; store unmasked rows; shuffle-reduce; atomic per row.
#pragma unroll
    for (int fm = 0; fm < 4; ++fm)
#pragma unroll
        for (int r = 0; r < 4; ++r) {
            const int nloc = nr + fm * 16 + (l >> 4) * 4 + r;
            const bool msk = maskS[nloc] != 0;
            float* rowp = attL + ((size_t)bh * SEQ + n0 + nloc) * SEQ + m0 + mcw + l15;
            float s = 0.f;
#pragma unroll
            for (int fn = 0; fn < 4; ++fn) {
                const float e = __expf(acc[fm][fn][r]);
                s += e;
                if (!msk) rowp[fn * 16] = e;
            }
            s += __shfl_xor(s, 1); s += __shfl_xor(s, 2);
            s += __shfl_xor(s, 4); s += __shfl_xor(s, 8);
            if (!msk && l15 == 0)
                atomicAdd(rowSum + (size_t)bh * SEQ + n0 + nloc, s);
        }
}

// ---------------------------------------------------------------------------
// Normalize (E -> p fp32 att output) + PV via bf16 MFMA (p hi-only, V hi+lo).
// 1D grid with XCD-chunked swizzle (r14 win: V panel cached once per XCD L2).
// AO emitted bf16 hi/lo.
// ---------------------------------------------------------------------------
__global__ __launch_bounds__(256) void pv_mfma(
    float* __restrict__ attL,
    const short* __restrict__ VThi,
    const short* __restrict__ VTlo,
    const int* __restrict__ mask,
    const float* __restrict__ rowSum,
    short* __restrict__ AOhi,
    short* __restrict__ AOlo)
{
    constexpr int LDP = 72;
    __shared__ short pHi[128 * LDP];
    __shared__ short sVh[64 * LDP];
    __shared__ short sVl[64 * LDP];
    __shared__ float rowInv[128];
    __shared__ int   maskS[128];

    // swizzle: flat = (bid%64)*8 + bid/64; group g = flat/8 gets 8 blocks all
    // with bid ≡ g/8 (mod 8) -> one XCD. flat -> (n0i, h, b).
    const int bid  = blockIdx.x;
    const int flat = (bid & 63) * 8 + (bid >> 6);
    const int n0   = (flat & 7) * 128;
    const int h    = (flat >> 3) & 15;
    const int b    = flat >> 7;

    const int t   = threadIdx.x;
    const int w   = t >> 6;
    const int l   = t & 63;
    const int l15 = l & 15;
    const int lk  = (l >> 4) * 8;
    const int bh  = b * NHEADS + h;
    float* Lbase = attL + ((size_t)bh * SEQ + n0) * SEQ;

    if (t < 128) {
        const int mk = mask[b * SEQ + n0 + t];
        maskS[t] = mk;
        rowInv[t] = mk ? 0.f : 1.0f / rowSum[(size_t)bh * SEQ + n0 + t];
    }
    __syncthreads();

    const int nr = (w >> 1) * 64;   // wave n base
    const int dc = (w & 1) * 32;    // wave d base

    f32x4 acc[4][2];
#pragma unroll
    for (int i = 0; i < 4; ++i)
#pragma unroll
        for (int j = 0; j < 2; ++j) acc[i][j] = f32x4{0.f, 0.f, 0.f, 0.f};

    // prefetch chunk 0 E values (8 float4/thread covering [128 n][64 m])
    float4 sreg[8];
#pragma unroll
    for (int i = 0; i < 8; ++i) sreg[i] = make_float4(0.f, 0.f, 0.f, 0.f);
#pragma unroll
    for (int i = 0; i < 8; ++i) {
        const int f4 = t + i * 256;
        const int row = f4 >> 4, mq = f4 & 15;
        if (!maskS[row])
            sreg[i] = *reinterpret_cast<const float4*>(
                Lbase + (size_t)row * SEQ + mq * 4);
    }

    for (int mc = 0; mc < 16; ++mc) {
        // produce p: fp32 att write + bf16-RNE into LDS (A-op, hi only)
#pragma unroll
        for (int i = 0; i < 8; ++i) {
            const int f4 = t + i * 256;
            const int row = f4 >> 4, mq = f4 & 15;
            float4 p4;
            if (maskS[row]) {
                p4.x = PCONST; p4.y = PCONST; p4.z = PCONST; p4.w = PCONST;
            } else {
                const float iv = rowInv[row];
                p4.x = sreg[i].x * iv; p4.y = sreg[i].y * iv;
                p4.z = sreg[i].z * iv; p4.w = sreg[i].w * iv;
            }
            *reinterpret_cast<float4*>(
                Lbase + (size_t)row * SEQ + mc * 64 + mq * 4) = p4;
            bf16x4 hv;
            hv[0] = f2bf_rne(p4.x); hv[1] = f2bf_rne(p4.y);
            hv[2] = f2bf_rne(p4.z); hv[3] = f2bf_rne(p4.w);
            *(bf16x4*)(pHi + row * LDP + mq * 4) = hv;
        }
        // stage VT chunk [64 d][64 m]
#pragma unroll
        for (int i = 0; i < 2; ++i) {
            const int f = t + i * 256;
            const int d = f >> 3, m8 = f & 7;
            const size_t src = ((size_t)bh * HDIM + d) * SEQ + mc * 64 + m8 * 8;
            *(bf16x8*)(sVh + d * LDP + m8 * 8) = *(const bf16x8*)(VThi + src);
            *(bf16x8*)(sVl + d * LDP + m8 * 8) = *(const bf16x8*)(VTlo + src);
        }
        __syncthreads();

        // prefetch next chunk's E under this chunk's MFMAs
        if (mc + 1 < 16) {
#pragma unroll
            for (int i = 0; i < 8; ++i) {
                const int f4 = t + i * 256;
                const int row = f4 >> 4, mq = f4 & 15;
                if (!maskS[row])
                    sreg[i] = *reinterpret_cast<const float4*>(
                        Lbase + (size_t)row * SEQ + (mc + 1) * 64 + mq * 4);
            }
        }

        // MFMA: D[n][d] += p_hi[n][m] * (V_hi + V_lo)[m][d]
#pragma unroll
        for (int ks = 0; ks < 2; ++ks) {
            bf16x8 ah[4], bhv[2], blo[2];
#pragma unroll
            for (int fm = 0; fm < 4; ++fm) {
                const int off = (nr + fm * 16 + l15) * LDP + ks * 32 + lk;
                ah[fm] = *(const bf16x8*)(pHi + off);
            }
#pragma unroll
            for (int fn = 0; fn < 2; ++fn) {
                const int off = (dc + fn * 16 + l15) * LDP + ks * 32 + lk;
                bhv[fn] = *(const bf16x8*)(sVh + off);
                blo[fn] = *(const bf16x8*)(sVl + off);
            }
#pragma unroll
            for (int fm = 0; fm < 4; ++fm)
#pragma unroll
                for (int fn = 0; fn < 2; ++fn) {
                    acc[fm][fn] = __builtin_amdgcn_mfma_f32_16x16x32_bf16(
                        ah[fm], bhv[fn], acc[fm][fn], 0, 0, 0);
                    acc[fm][fn] = __builtin_amdgcn_mfma_f32_16x16x32_bf16(
                        ah[fm], blo[fn], acc[fm][fn], 0, 0, 0);
                }
        }
        __syncthreads();
    }

    // epilogue: row = (l>>4)*4 + r (n), col = l15 (d) — emit hi/lo bf16
#pragma unroll
    for (int fm = 0; fm < 4; ++fm)
#pragma unroll
        for (int fn = 0; fn < 2; ++fn) {
            const int dd = dc + fn * 16 + l15;
#pragma unroll
            for (int r = 0; r < 4; ++r) {
                const int n = n0 + nr + fm * 16 + (l >> 4) * 4 + r;
                const size_t idx =
                    ((size_t)(b * SEQ + n)) * DMODEL + h * HDIM + dd;
                short hi, lo; split_bf16(acc[fm][fn][r], hi, lo);
                AOhi[idx] = hi; AOlo[idx] = lo;
            }
        }
}

// ---------------------------------------------------------------------------
extern "C" void kernel_launch(void* const* d_in, const int* in_sizes, int n_in,
                              void* d_out, int out_size, void* d_ws, size_t ws_size,
                              hipStream_t stream) {
    const float* q       = (const float*)d_in[0];
    const float* k       = (const float*)d_in[1];
    const float* v       = (const float*)d_in[2];
    const int*   mask    = (const int*)d_in[3];
    const float* dists   = (const float*)d_in[4];
    const float* weights = (const float*)d_in[5];
    const float* biases  = (const float*)d_in[6];
    const float* wg      = (const float*)d_in[7];

    float* out  = (float*)d_out;
    float* attL = out + (size_t)BATCH * SEQ * DMODEL;          // att region of d_out

    const size_t HSZ = (size_t)BATCH * NHEADS * SEQ * HDIM;    // 4,194,304
    const size_t WSZ = (size_t)4 * DMODEL * DMODEL;            // 4,194,304
    short* Qhi  = (short*)d_ws;
    short* Qlo  = Qhi + HSZ;
    short* Khi  = Qlo + HSZ;
    short* Klo  = Khi + HSZ;
    short* VThi = Klo + HSZ;
    short* VTlo = VThi + HSZ;
    short* Whi  = VTlo + HSZ;
    short* Wlo  = Whi + WSZ;          // total 32M shorts = 64 MB
    short* AOhi = Qhi;                // alias: Q dead after qk_mfma
    short* AOlo = Qlo;
    float* rowSum = out;              // out[0:64K] — overwritten by final proj

    const size_t DD = (size_t)DMODEL * DMODEL;
    const int NROWS = BATCH * NHEADS * SEQ;                    // 65536

    prep_split<<<(int)(WSZ / 8 / 256), 256, 0, stream>>>(weights, Whi, Wlo);
    zero_f32<<<(NROWS + 255) / 256, 256, 0, stream>>>(rowSum, NROWS);

    dim3 gProj(DMODEL / 64, (BATCH * SEQ) / 128);              // (16, 32)
    proj_mfma<0, 2><<<gProj, 256, 0, stream>>>(q, nullptr, nullptr,
        Whi, Wlo, biases, nullptr, Qhi, Qlo, QK_SCALE);
    proj_mfma<0, 2><<<gProj, 256, 0, stream>>>(k, nullptr, nullptr,
        Whi + DD, Wlo + DD, biases + DMODEL, nullptr, Khi, Klo, 1.0f);
    proj_mfma<0, 3><<<gProj, 256, 0, stream>>>(v, nullptr, nullptr,
        Whi + 2 * DD, Wlo + 2 * DD, biases + 2 * DMODEL, nullptr, VThi, VTlo, 1.0f);

    // qk (fused graph bias): 1D grid of 4096, head-grouped XCD swizzle
    qk_mfma<<<(SEQ / 128) * (SEQ / 128) * BATCH * NHEADS, 256, 0, stream>>>(
        Qhi, Qlo, Khi, Klo, dists, wg, mask, attL, rowSum);

    // pv: 1D grid of 512 with XCD-chunked swizzle (see kernel comment)
    pv_mfma<<<(SEQ / 128) * NHEADS * BATCH, 256, 0, stream>>>(
        attL, VThi, VTlo, mask, rowSum, AOhi, AOlo);

    proj_mfma<1, 0><<<gProj, 256, 0, stream>>>(nullptr, AOhi, AOlo,
        Whi + 3 * DD, Wlo + 3 * DD, biases + 3 * DMODEL, out, nullptr, nullptr, 1.0f);
}

// Round 18
// 417.318 us; speedup vs baseline: 1.2786x; 1.2786x over previous
//
#include <hip/hip_runtime.h>
#include <hip/hip_bf16.h>

#define SEQ      1024
#define BATCH    4
#define NHEADS   16
#define HDIM     64
#define DMODEL   1024
#define DGRAPH   8
#define QK_SCALE 0.125f
#define PCONST   0.0009765625f   /* 1/1024 exact */

typedef __attribute__((ext_vector_type(8))) short bf16x8;
typedef __attribute__((ext_vector_type(4))) short bf16x4;
typedef __attribute__((ext_vector_type(4))) float f32x4;

__device__ __forceinline__ void split_bf16(float x, short& hi, short& lo) {
    unsigned u = __float_as_uint(x);
    hi = (short)(u >> 16);                         // truncated high part
    float hf = __uint_as_float(u & 0xffff0000u);
    lo = (short)(__float_as_uint(x - hf) >> 16);   // residual, truncated
}

__device__ __forceinline__ short f2bf_rne(float x) {   // RNE bf16
    unsigned u = __float_as_uint(x);
    u += 0x7fffu + ((u >> 16) & 1u);
    return (short)(u >> 16);
}

// ---------------------------------------------------------------------------
// One-time hi/lo split of the fused weight matrix (4M floats).
// ---------------------------------------------------------------------------
__global__ __launch_bounds__(256) void prep_split(
    const float* __restrict__ X, short* __restrict__ Hi, short* __restrict__ Lo)
{
    const int idx = blockIdx.x * 256 + threadIdx.x;
    const float* p = X + (size_t)idx * 8;
    float4 u0 = *(const float4*)p;
    float4 u1 = *(const float4*)(p + 4);
    float v[8] = {u0.x, u0.y, u0.z, u0.w, u1.x, u1.y, u1.z, u1.w};
    bf16x8 hv, lv;
#pragma unroll
    for (int j = 0; j < 8; ++j) {
        short h, s; split_bf16(v[j], h, s);
        hv[j] = h; lv[j] = s;
    }
    *(bf16x8*)(Hi + (size_t)idx * 8) = hv;
    *(bf16x8*)(Lo + (size_t)idx * 8) = lv;
}

// ---------------------------------------------------------------------------
// Split-bf16 MFMA projection (structure proven r5-r12, unchanged).
// INMODE 0: X fp32 (split in staging)    INMODE 1: X pre-split (Xhi/Xlo)
// OUTMODE 0: fp32 flat [m][DMODEL]
// OUTMODE 2: bf16 hi/lo headsplit [b][h][n][d]
// OUTMODE 3: bf16 hi/lo head-transposed [b][h][d][n]
// ---------------------------------------------------------------------------
template<int INMODE, int OUTMODE>
__global__ __launch_bounds__(256) void proj_mfma(
    const float* __restrict__ X,
    const short* __restrict__ Xhi, const short* __restrict__ Xlo,
    const short* __restrict__ Whi, const short* __restrict__ Wlo,
    const float* __restrict__ bias,
    float* __restrict__ Yf,
    short* __restrict__ Yhi,
    short* __restrict__ Ylo,
    float scale)
{
    constexpr int LDK = 40;
    __shared__ short Ah[128 * LDK];
    __shared__ short Al[128 * LDK];
    __shared__ short Bh[64 * LDK];
    __shared__ short Bl[64 * LDK];

    const int t   = threadIdx.x;
    const int w   = t >> 6;
    const int l   = t & 63;
    const int l15 = l & 15;
    const int lk  = (l >> 4) * 8;
    const int m0  = blockIdx.y * 128;
    const int c0  = blockIdx.x * 64;
    const int wr  = (w >> 1) * 64;
    const int wc  = (w & 1) * 32;

    const int srow = t >> 2;
    const int skg  = t & 3;

    f32x4 acc[4][2];
#pragma unroll
    for (int i = 0; i < 4; ++i)
#pragma unroll
        for (int j = 0; j < 2; ++j) acc[i][j] = f32x4{0.f, 0.f, 0.f, 0.f};

    float  xa[2][8];
    bf16x8 xh[2], xl[2];
    bf16x8 wh, wl;

    if constexpr (INMODE == 0) {
#pragma unroll
        for (int i = 0; i < 2; ++i) {
            const float* p = X + (size_t)(m0 + srow + i * 64) * DMODEL + skg * 8;
            float4 u0 = *(const float4*)p;
            float4 u1 = *(const float4*)(p + 4);
            xa[i][0] = u0.x; xa[i][1] = u0.y; xa[i][2] = u0.z; xa[i][3] = u0.w;
            xa[i][4] = u1.x; xa[i][5] = u1.y; xa[i][6] = u1.z; xa[i][7] = u1.w;
        }
    } else {
#pragma unroll
        for (int i = 0; i < 2; ++i) {
            const size_t off = (size_t)(m0 + srow + i * 64) * DMODEL + skg * 8;
            xh[i] = *(const bf16x8*)(Xhi + off);
            xl[i] = *(const bf16x8*)(Xlo + off);
        }
    }
    {
        const size_t off = (size_t)(c0 + srow) * DMODEL + skg * 8;
        wh = *(const bf16x8*)(Whi + off);
        wl = *(const bf16x8*)(Wlo + off);
    }

    for (int kt = 0; kt < 32; ++kt) {
        if constexpr (INMODE == 0) {
#pragma unroll
            for (int i = 0; i < 2; ++i) {
                bf16x8 hv, lv;
#pragma unroll
                for (int j = 0; j < 8; ++j) {
                    short h, s; split_bf16(xa[i][j], h, s);
                    hv[j] = h; lv[j] = s;
                }
                *(bf16x8*)(Ah + (srow + i * 64) * LDK + skg * 8) = hv;
                *(bf16x8*)(Al + (srow + i * 64) * LDK + skg * 8) = lv;
            }
        } else {
#pragma unroll
            for (int i = 0; i < 2; ++i) {
                *(bf16x8*)(Ah + (srow + i * 64) * LDK + skg * 8) = xh[i];
                *(bf16x8*)(Al + (srow + i * 64) * LDK + skg * 8) = xl[i];
            }
        }
        *(bf16x8*)(Bh + srow * LDK + skg * 8) = wh;
        *(bf16x8*)(Bl + srow * LDK + skg * 8) = wl;
        __syncthreads();

        if (kt + 1 < 32) {
            const int k0 = (kt + 1) * 32;
            if constexpr (INMODE == 0) {
#pragma unroll
                for (int i = 0; i < 2; ++i) {
                    const float* p = X + (size_t)(m0 + srow + i * 64) * DMODEL + k0 + skg * 8;
                    float4 u0 = *(const float4*)p;
                    float4 u1 = *(const float4*)(p + 4);
                    xa[i][0] = u0.x; xa[i][1] = u0.y; xa[i][2] = u0.z; xa[i][3] = u0.w;
                    xa[i][4] = u1.x; xa[i][5] = u1.y; xa[i][6] = u1.z; xa[i][7] = u1.w;
                }
            } else {
#pragma unroll
                for (int i = 0; i < 2; ++i) {
                    const size_t off = (size_t)(m0 + srow + i * 64) * DMODEL + k0 + skg * 8;
                    xh[i] = *(const bf16x8*)(Xhi + off);
                    xl[i] = *(const bf16x8*)(Xlo + off);
                }
            }
            const size_t off = (size_t)(c0 + srow) * DMODEL + k0 + skg * 8;
            wh = *(const bf16x8*)(Whi + off);
            wl = *(const bf16x8*)(Wlo + off);
        }

        bf16x8 ah[4], alo[4], bh[2], blo[2];
#pragma unroll
        for (int fm = 0; fm < 4; ++fm) {
            const int off = (wr + fm * 16 + l15) * LDK + lk;
            ah[fm]  = *(const bf16x8*)(Ah + off);
            alo[fm] = *(const bf16x8*)(Al + off);
        }
#pragma unroll
        for (int fn = 0; fn < 2; ++fn) {
            const int off = (wc + fn * 16 + l15) * LDK + lk;
            bh[fn]  = *(const bf16x8*)(Bh + off);
            blo[fn] = *(const bf16x8*)(Bl + off);
        }
#pragma unroll
        for (int fm = 0; fm < 4; ++fm)
#pragma unroll
            for (int fn = 0; fn < 2; ++fn) {
                acc[fm][fn] = __builtin_amdgcn_mfma_f32_16x16x32_bf16(
                    ah[fm], bh[fn], acc[fm][fn], 0, 0, 0);
                acc[fm][fn] = __builtin_amdgcn_mfma_f32_16x16x32_bf16(
                    ah[fm], blo[fn], acc[fm][fn], 0, 0, 0);
                acc[fm][fn] = __builtin_amdgcn_mfma_f32_16x16x32_bf16(
                    alo[fm], bh[fn], acc[fm][fn], 0, 0, 0);
            }
        __syncthreads();
    }

    // epilogue: C/D layout col = l&15, row = (l>>4)*4 + r
#pragma unroll
    for (int fm = 0; fm < 4; ++fm)
#pragma unroll
        for (int fn = 0; fn < 2; ++fn) {
            const int c = c0 + wc + fn * 16 + l15;
            const float bb = bias[c];
#pragma unroll
            for (int r = 0; r < 4; ++r) {
                const int m = m0 + wr + fm * 16 + (l >> 4) * 4 + r;
                const float v = (acc[fm][fn][r] + bb) * scale;
                if constexpr (OUTMODE == 0) {
                    Yf[(size_t)m * DMODEL + c] = v;
                } else {
                    const int b_ = m >> 10, n = m & 1023;
                    const int h = c >> 6, d = c & 63;
                    short hi, lo; split_bf16(v, hi, lo);
                    if constexpr (OUTMODE == 2) {
                        const size_t idx =
                            ((size_t)((b_ * NHEADS + h) * SEQ + n)) * HDIM + d;
                        Yhi[idx] = hi; Ylo[idx] = lo;
                    } else {  // OUTMODE 3: transposed [b][h][d][n]
                        const size_t idx =
                            ((size_t)((b_ * NHEADS + h) * HDIM + d)) * SEQ + n;
                        Yhi[idx] = hi; Ylo[idx] = lo;
                    }
                }
            }
        }
}

// ---------------------------------------------------------------------------
// Graph bias (fp32) -> attL; zeroes rowSum; masked rows early-exit.
// Reads dists exactly once by construction.
// ---------------------------------------------------------------------------
__global__ __launch_bounds__(256) void graph_bias_kernel(
    const float* __restrict__ dists,
    const float* __restrict__ wg,
    const int* __restrict__ mask,
    float* __restrict__ attL,
    float* __restrict__ rowSum)
{
    const int n = blockIdx.x & 1023;
    const int b = blockIdx.x >> 10;
    const int t = threadIdx.x;
    if (t < NHEADS)
        rowSum[(size_t)(b * NHEADS + t) * SEQ + n] = 0.f;
    if (mask[b * SEQ + n]) return;

    __shared__ float wgs[NHEADS * DGRAPH];
    if (t < NHEADS * DGRAPH) wgs[t] = wg[t];
    __syncthreads();

    const int m = t * 4;
    const float* dp = dists + (((size_t)(b * SEQ + n)) * SEQ + m) * DGRAPH;
    float d[4][8];
#pragma unroll
    for (int i = 0; i < 8; ++i) {
        float4 v = *reinterpret_cast<const float4*>(dp + i * 4);
        d[i >> 1][(i & 1) * 4 + 0] = v.x; d[i >> 1][(i & 1) * 4 + 1] = v.y;
        d[i >> 1][(i & 1) * 4 + 2] = v.z; d[i >> 1][(i & 1) * 4 + 3] = v.w;
    }
#pragma unroll
    for (int h = 0; h < NHEADS; ++h) {
        float ov[4];
#pragma unroll
        for (int jm = 0; jm < 4; ++jm) {
            float s = 0.f;
#pragma unroll
            for (int p = 0; p < DGRAPH; ++p)
                s = fmaf(d[jm][p], wgs[h * DGRAPH + p], s);
            ov[jm] = s;
        }
        float4 o; o.x = ov[0]; o.y = ov[1]; o.z = ov[2]; o.w = ov[3];
        *reinterpret_cast<float4*>(
            attL + (((size_t)((b * NHEADS + h) * SEQ + n)) * SEQ + m)) = o;
    }
}

// ---------------------------------------------------------------------------
// MFMA QK^T + exp + row-sum (r14 proven form: Q and K both LDS-staged).
// 1D grid with XCD-chunked swizzle: all 64 (m0,n0) blocks of one bh land on
// the SAME XCD (bid ≡ bh mod 8) -> that head's Q/K panels (~1 MB) stay
// L2-warm across the group. Masked rows: no bias read, no store, no atomic.
// ---------------------------------------------------------------------------
__global__ __launch_bounds__(256) void qk_mfma(
    const short* __restrict__ Qhi, const short* __restrict__ Qlo,
    const short* __restrict__ Khi, const short* __restrict__ Klo,
    const int* __restrict__ mask,
    float* __restrict__ attL,
    float* __restrict__ rowSum)
{
    constexpr int LDK = 72;
    __shared__ short sQh[128 * LDK];
    __shared__ short sQl[128 * LDK];
    __shared__ short sKh[128 * LDK];
    __shared__ short sKl[128 * LDK];
    __shared__ int maskS[128];

    // swizzle: bh = (bid>>9)*8 + (bid&7); j = (bid>>3)&63; bijective on [0,4096)
    const int bid = blockIdx.x;
    const int bh  = ((bid >> 9) << 3) | (bid & 7);
    const int j   = (bid >> 3) & 63;
    const int m0  = (j & 7) * 128;
    const int n0  = (j >> 3) * 128;
    const int b   = bh >> 4;

    const int t   = threadIdx.x;
    const int w   = t >> 6;
    const int l   = t & 63;
    const int l15 = l & 15;
    const int lk  = (l >> 4) * 8;

    if (t < 128) maskS[t] = mask[b * SEQ + n0 + t];

    // stage Q/K hi+lo tiles [128][64] bf16 -> padded LDS rows (LDK=72)
#pragma unroll
    for (int it = 0; it < 4; ++it) {
        const int f   = t + it * 256;
        const int row = f >> 3;
        const int c8  = f & 7;
        const size_t gq = ((size_t)bh * SEQ + n0 + row) * HDIM + c8 * 8;
        const size_t gk = ((size_t)bh * SEQ + m0 + row) * HDIM + c8 * 8;
        const int lo = row * LDK + c8 * 8;
        *(bf16x8*)(sQh + lo) = *(const bf16x8*)(Qhi + gq);
        *(bf16x8*)(sQl + lo) = *(const bf16x8*)(Qlo + gq);
        *(bf16x8*)(sKh + lo) = *(const bf16x8*)(Khi + gk);
        *(bf16x8*)(sKl + lo) = *(const bf16x8*)(Klo + gk);
    }
    __syncthreads();   // maskS + LDS tiles ready

    const int nr  = (w >> 1) * 64;   // wave n base
    const int mcw = (w & 1) * 64;    // wave m base

    // acc init = graph bias tile (fp32), masked rows -> 0 (no load)
    f32x4 acc[4][4];
    {
        const float* bb = attL + ((size_t)bh * SEQ + n0 + nr + (l >> 4) * 4) * SEQ
                          + m0 + mcw + l15;
#pragma unroll
        for (int fm = 0; fm < 4; ++fm)
#pragma unroll
            for (int r = 0; r < 4; ++r) {
                const int nloc = nr + fm * 16 + (l >> 4) * 4 + r;
                const bool mk = maskS[nloc] != 0;
#pragma unroll
                for (int fn = 0; fn < 4; ++fn)
                    acc[fm][fn][r] =
                        mk ? 0.f : bb[(size_t)(fm * 16 + r) * SEQ + fn * 16];
            }
    }

#pragma unroll
    for (int ks = 0; ks < 2; ++ks) {
        bf16x8 ah[4], alo[4], bhv[4], blo[4];
#pragma unroll
        for (int fm = 0; fm < 4; ++fm) {
            const int off = (nr + fm * 16 + l15) * LDK + ks * 32 + lk;
            ah[fm]  = *(const bf16x8*)(sQh + off);
            alo[fm] = *(const bf16x8*)(sQl + off);
        }
#pragma unroll
        for (int fn = 0; fn < 4; ++fn) {
            const int off = (mcw + fn * 16 + l15) * LDK + ks * 32 + lk;
            bhv[fn] = *(const bf16x8*)(sKh + off);
            blo[fn] = *(const bf16x8*)(sKl + off);
        }
#pragma unroll
        for (int fm = 0; fm < 4; ++fm)
#pragma unroll
            for (int fn = 0; fn < 4; ++fn) {
                acc[fm][fn] = __builtin_amdgcn_mfma_f32_16x16x32_bf16(
                    ah[fm], bhv[fn], acc[fm][fn], 0, 0, 0);
                acc[fm][fn] = __builtin_amdgcn_mfma_f32_16x16x32_bf16(
                    ah[fm], blo[fn], acc[fm][fn], 0, 0, 0);
                acc[fm][fn] = __builtin_amdgcn_mfma_f32_16x16x32_bf16(
                    alo[fm], bhv[fn], acc[fm][fn], 0, 0, 0);
            }
    }

    // E = exp(S) fp32; store unmasked rows; shuffle-reduce; atomic per row.
#pragma unroll
    for (int fm = 0; fm < 4; ++fm)
#pragma unroll
        for (int r = 0; r < 4; ++r) {
            const int nloc = nr + fm * 16 + (l >> 4) * 4 + r;
            const bool msk = maskS[nloc] != 0;
            float* rowp = attL + ((size_t)bh * SEQ + n0 + nloc) * SEQ + m0 + mcw + l15;
            float s = 0.f;
#pragma unroll
            for (int fn = 0; fn < 4; ++fn) {
                const float e = __expf(acc[fm][fn][r]);
                s += e;
                if (!msk) rowp[fn * 16] = e;
            }
            s += __shfl_xor(s, 1); s += __shfl_xor(s, 2);
            s += __shfl_xor(s, 4); s += __shfl_xor(s, 8);
            if (!msk && l15 == 0)
                atomicAdd(rowSum + (size_t)bh * SEQ + n0 + nloc, s);
        }
}

// ---------------------------------------------------------------------------
// Normalize (E -> p fp32 att output) + PV via bf16 MFMA (p hi-only, V hi+lo).
// 1D grid with XCD-chunked swizzle (r14 win: V panel cached once per XCD L2).
// AO emitted bf16 hi/lo.
// ---------------------------------------------------------------------------
__global__ __launch_bounds__(256) void pv_mfma(
    float* __restrict__ attL,
    const short* __restrict__ VThi,
    const short* __restrict__ VTlo,
    const int* __restrict__ mask,
    const float* __restrict__ rowSum,
    short* __restrict__ AOhi,
    short* __restrict__ AOlo)
{
    constexpr int LDP = 72;
    __shared__ short pHi[128 * LDP];
    __shared__ short sVh[64 * LDP];
    __shared__ short sVl[64 * LDP];
    __shared__ float rowInv[128];
    __shared__ int   maskS[128];

    // swizzle: flat = (bid%64)*8 + bid/64; group g = flat/8 gets 8 blocks all
    // with bid ≡ g/8 (mod 8) -> one XCD. flat -> (n0i, h, b).
    const int bid  = blockIdx.x;
    const int flat = (bid & 63) * 8 + (bid >> 6);
    const int n0   = (flat & 7) * 128;
    const int h    = (flat >> 3) & 15;
    const int b    = flat >> 7;

    const int t   = threadIdx.x;
    const int w   = t >> 6;
    const int l   = t & 63;
    const int l15 = l & 15;
    const int lk  = (l >> 4) * 8;
    const int bh  = b * NHEADS + h;
    float* Lbase = attL + ((size_t)bh * SEQ + n0) * SEQ;

    if (t < 128) {
        const int mk = mask[b * SEQ + n0 + t];
        maskS[t] = mk;
        rowInv[t] = mk ? 0.f : 1.0f / rowSum[(size_t)bh * SEQ + n0 + t];
    }
    __syncthreads();

    const int nr = (w >> 1) * 64;   // wave n base
    const int dc = (w & 1) * 32;    // wave d base

    f32x4 acc[4][2];
#pragma unroll
    for (int i = 0; i < 4; ++i)
#pragma unroll
        for (int j = 0; j < 2; ++j) acc[i][j] = f32x4{0.f, 0.f, 0.f, 0.f};

    // prefetch chunk 0 E values (8 float4/thread covering [128 n][64 m])
    float4 sreg[8];
#pragma unroll
    for (int i = 0; i < 8; ++i) sreg[i] = make_float4(0.f, 0.f, 0.f, 0.f);
#pragma unroll
    for (int i = 0; i < 8; ++i) {
        const int f4 = t + i * 256;
        const int row = f4 >> 4, mq = f4 & 15;
        if (!maskS[row])
            sreg[i] = *reinterpret_cast<const float4*>(
                Lbase + (size_t)row * SEQ + mq * 4);
    }

    for (int mc = 0; mc < 16; ++mc) {
        // produce p: fp32 att write + bf16-RNE into LDS (A-op, hi only)
#pragma unroll
        for (int i = 0; i < 8; ++i) {
            const int f4 = t + i * 256;
            const int row = f4 >> 4, mq = f4 & 15;
            float4 p4;
            if (maskS[row]) {
                p4.x = PCONST; p4.y = PCONST; p4.z = PCONST; p4.w = PCONST;
            } else {
                const float iv = rowInv[row];
                p4.x = sreg[i].x * iv; p4.y = sreg[i].y * iv;
                p4.z = sreg[i].z * iv; p4.w = sreg[i].w * iv;
            }
            *reinterpret_cast<float4*>(
                Lbase + (size_t)row * SEQ + mc * 64 + mq * 4) = p4;
            bf16x4 hv;
            hv[0] = f2bf_rne(p4.x); hv[1] = f2bf_rne(p4.y);
            hv[2] = f2bf_rne(p4.z); hv[3] = f2bf_rne(p4.w);
            *(bf16x4*)(pHi + row * LDP + mq * 4) = hv;
        }
        // stage VT chunk [64 d][64 m]
#pragma unroll
        for (int i = 0; i < 2; ++i) {
            const int f = t + i * 256;
            const int d = f >> 3, m8 = f & 7;
            const size_t src = ((size_t)bh * HDIM + d) * SEQ + mc * 64 + m8 * 8;
            *(bf16x8*)(sVh + d * LDP + m8 * 8) = *(const bf16x8*)(VThi + src);
            *(bf16x8*)(sVl + d * LDP + m8 * 8) = *(const bf16x8*)(VTlo + src);
        }
        __syncthreads();

        // prefetch next chunk's E under this chunk's MFMAs
        if (mc + 1 < 16) {
#pragma unroll
            for (int i = 0; i < 8; ++i) {
                const int f4 = t + i * 256;
                const int row = f4 >> 4, mq = f4 & 15;
                if (!maskS[row])
                    sreg[i] = *reinterpret_cast<const float4*>(
                        Lbase + (size_t)row * SEQ + (mc + 1) * 64 + mq * 4);
            }
        }

        // MFMA: D[n][d] += p_hi[n][m] * (V_hi + V_lo)[m][d]
#pragma unroll
        for (int ks = 0; ks < 2; ++ks) {
            bf16x8 ah[4], bhv[2], blo[2];
#pragma unroll
            for (int fm = 0; fm < 4; ++fm) {
                const int off = (nr + fm * 16 + l15) * LDP + ks * 32 + lk;
                ah[fm] = *(const bf16x8*)(pHi + off);
            }
#pragma unroll
            for (int fn = 0; fn < 2; ++fn) {
                const int off = (dc + fn * 16 + l15) * LDP + ks * 32 + lk;
                bhv[fn] = *(const bf16x8*)(sVh + off);
                blo[fn] = *(const bf16x8*)(sVl + off);
            }
#pragma unroll
            for (int fm = 0; fm < 4; ++fm)
#pragma unroll
                for (int fn = 0; fn < 2; ++fn) {
                    acc[fm][fn] = __builtin_amdgcn_mfma_f32_16x16x32_bf16(
                        ah[fm], bhv[fn], acc[fm][fn], 0, 0, 0);
                    acc[fm][fn] = __builtin_amdgcn_mfma_f32_16x16x32_bf16(
                        ah[fm], blo[fn], acc[fm][fn], 0, 0, 0);
                }
        }
        __syncthreads();
    }

    // epilogue: row = (l>>4)*4 + r (n), col = l15 (d) — emit hi/lo bf16
#pragma unroll
    for (int fm = 0; fm < 4; ++fm)
#pragma unroll
        for (int fn = 0; fn < 2; ++fn) {
            const int dd = dc + fn * 16 + l15;
#pragma unroll
            for (int r = 0; r < 4; ++r) {
                const int n = n0 + nr + fm * 16 + (l >> 4) * 4 + r;
                const size_t idx =
                    ((size_t)(b * SEQ + n)) * DMODEL + h * HDIM + dd;
                short hi, lo; split_bf16(acc[fm][fn][r], hi, lo);
                AOhi[idx] = hi; AOlo[idx] = lo;
            }
        }
}

// ---------------------------------------------------------------------------
extern "C" void kernel_launch(void* const* d_in, const int* in_sizes, int n_in,
                              void* d_out, int out_size, void* d_ws, size_t ws_size,
                              hipStream_t stream) {
    const float* q       = (const float*)d_in[0];
    const float* k       = (const float*)d_in[1];
    const float* v       = (const float*)d_in[2];
    const int*   mask    = (const int*)d_in[3];
    const float* dists   = (const float*)d_in[4];
    const float* weights = (const float*)d_in[5];
    const float* biases  = (const float*)d_in[6];
    const float* wg      = (const float*)d_in[7];

    float* out  = (float*)d_out;
    float* attL = out + (size_t)BATCH * SEQ * DMODEL;          // att region of d_out

    const size_t HSZ = (size_t)BATCH * NHEADS * SEQ * HDIM;    // 4,194,304
    const size_t WSZ = (size_t)4 * DMODEL * DMODEL;            // 4,194,304
    short* Qhi  = (short*)d_ws;
    short* Qlo  = Qhi + HSZ;
    short* Khi  = Qlo + HSZ;
    short* Klo  = Khi + HSZ;
    short* VThi = Klo + HSZ;
    short* VTlo = VThi + HSZ;
    short* Whi  = VTlo + HSZ;
    short* Wlo  = Whi + WSZ;          // total 32M shorts = 64 MB
    short* AOhi = Qhi;                // alias: Q dead after qk_mfma
    short* AOlo = Qlo;
    float* rowSum = out;              // out[0:64K] — overwritten by final proj

    const size_t DD = (size_t)DMODEL * DMODEL;

    prep_split<<<(int)(WSZ / 8 / 256), 256, 0, stream>>>(weights, Whi, Wlo);

    graph_bias_kernel<<<BATCH * SEQ, 256, 0, stream>>>(dists, wg, mask, attL, rowSum);

    dim3 gProj(DMODEL / 64, (BATCH * SEQ) / 128);              // (16, 32)
    proj_mfma<0, 2><<<gProj, 256, 0, stream>>>(q, nullptr, nullptr,
        Whi, Wlo, biases, nullptr, Qhi, Qlo, QK_SCALE);
    proj_mfma<0, 2><<<gProj, 256, 0, stream>>>(k, nullptr, nullptr,
        Whi + DD, Wlo + DD, biases + DMODEL, nullptr, Khi, Klo, 1.0f);
    proj_mfma<0, 3><<<gProj, 256, 0, stream>>>(v, nullptr, nullptr,
        Whi + 2 * DD, Wlo + 2 * DD, biases + 2 * DMODEL, nullptr, VThi, VTlo, 1.0f);

    // qk: 1D grid of 4096 with XCD-chunked swizzle (see kernel comment)
    qk_mfma<<<(SEQ / 128) * (SEQ / 128) * BATCH * NHEADS, 256, 0, stream>>>(
        Qhi, Qlo, Khi, Klo, mask, attL, rowSum);

    // pv: 1D grid of 512 with XCD-chunked swizzle (see kernel comment)
    pv_mfma<<<(SEQ / 128) * NHEADS * BATCH, 256, 0, stream>>>(
        attL, VThi, VTlo, mask, rowSum, AOhi, AOlo);

    proj_mfma<1, 0><<<gProj, 256, 0, stream>>>(nullptr, AOhi, AOlo,
        Whi + 3 * DD, Wlo + 3 * DD, biases + 3 * DMODEL, out, nullptr, nullptr, 1.0f);
}